// Round 1
// baseline (190.918 us; speedup 1.0000x reference)
//
#include <hip/hip_runtime.h>

#define BATCH 262144
#define TILES (BATCH / 64)
#define ASTRIDE 280  // bf16 elems per LDS row: 560B = 16B-aligned, 2-way-bank-free
#define BH 33554432  // B*H

typedef __attribute__((ext_vector_type(8))) short bf16x8;
typedef __attribute__((ext_vector_type(4))) float f32x4;

__device__ __forceinline__ unsigned short f2bf(float f) {
  unsigned int u = __float_as_uint(f);
  u += 0x7fffu + ((u >> 16) & 1u);  // round-to-nearest-even
  return (unsigned short)(u >> 16);
}

__device__ __forceinline__ float fexp(float x) { return __builtin_amdgcn_exp2f(x * 1.44269504f); }
__device__ __forceinline__ float sigm(float x) { return __builtin_amdgcn_rcpf(1.f + fexp(-x)); }
__device__ __forceinline__ float ftanh(float x) { return 1.f - 2.f * __builtin_amdgcn_rcpf(1.f + fexp(2.f * x)); }

__global__ __launch_bounds__(512, 2) void lstm_fused(
    const float* __restrict__ X, const float* __restrict__ H0, const float* __restrict__ C0,
    const float* __restrict__ Wii, const float* __restrict__ Whi,
    const float* __restrict__ Wif, const float* __restrict__ Whf,
    const float* __restrict__ Wio, const float* __restrict__ Who,
    const float* __restrict__ Wig, const float* __restrict__ Whg,
    float* __restrict__ Out) {
  __shared__ unsigned short Abuf[64 * ASTRIDE];

  const int tid = threadIdx.x;
  const int wave = tid >> 6;
  const int lane = tid & 63;
  const int lrow = lane & 15;
  const int lk = (lane >> 4) * 8;       // k sub-offset within a 32-wide K tile
  const int hcol = wave * 16 + lrow;    // hidden column this lane produces

  const float* Wxp[4] = {Wii, Wif, Wio, Wig};
  const float* Whp[4] = {Whi, Whf, Who, Whg};

  // ---- load weight fragments once; resident in VGPRs for the whole kernel ----
  bf16x8 wf[4][8];
#pragma unroll
  for (int g = 0; g < 4; ++g) {
#pragma unroll
    for (int kk = 0; kk < 8; ++kk) {
      const int k = kk * 32 + lk;  // 0..255 over concat(x,h) K axis
      const float* src = (kk < 4) ? (Wxp[g] + hcol * 128 + k)
                                  : (Whp[g] + hcol * 128 + (k - 128));
      float4 lo = *(const float4*)src;
      float4 hi = *(const float4*)(src + 4);
      bf16x8 w;
      w[0] = (short)f2bf(lo.x); w[1] = (short)f2bf(lo.y);
      w[2] = (short)f2bf(lo.z); w[3] = (short)f2bf(lo.w);
      w[4] = (short)f2bf(hi.x); w[5] = (short)f2bf(hi.y);
      w[6] = (short)f2bf(hi.z); w[7] = (short)f2bf(hi.w);
      wf[g][kk] = w;
    }
  }

  for (int tile = blockIdx.x; tile < TILES; tile += gridDim.x) {
    const int row0 = tile * 64;

    // ---- stage 64 rows of concat(x, h_prev) into LDS as bf16 ----
    const float4* xin = (const float4*)(X + (size_t)row0 * 128);
    const float4* hin = (const float4*)(H0 + (size_t)row0 * 128);
#pragma unroll
    for (int j = 0; j < 4; ++j) {
      const int f = tid + j * 512;       // float4 index: fully coalesced
      const int r = f >> 5;
      const int c4 = (f & 31) * 4;
      float4 v = xin[f];
      ushort4 p;
      p.x = f2bf(v.x); p.y = f2bf(v.y); p.z = f2bf(v.z); p.w = f2bf(v.w);
      *(ushort4*)&Abuf[r * ASTRIDE + c4] = p;
      float4 u = hin[f];
      ushort4 q;
      q.x = f2bf(u.x); q.y = f2bf(u.y); q.z = f2bf(u.z); q.w = f2bf(u.w);
      *(ushort4*)&Abuf[r * ASTRIDE + 128 + c4] = q;
    }
    __syncthreads();

    // ---- 4 M-tiles of 16 rows: MFMA all 4 gates, then fused LSTM epilogue ----
#pragma unroll
    for (int mt = 0; mt < 4; ++mt) {
      f32x4 acc0 = {0.f, 0.f, 0.f, 0.f};
      f32x4 acc1 = acc0, acc2 = acc0, acc3 = acc0;
#pragma unroll
      for (int kk = 0; kk < 8; ++kk) {
        bf16x8 a = *(const bf16x8*)&Abuf[(mt * 16 + lrow) * ASTRIDE + kk * 32 + lk];
        acc0 = __builtin_amdgcn_mfma_f32_16x16x32_bf16(a, wf[0][kk], acc0, 0, 0, 0);
        acc1 = __builtin_amdgcn_mfma_f32_16x16x32_bf16(a, wf[1][kk], acc1, 0, 0, 0);
        acc2 = __builtin_amdgcn_mfma_f32_16x16x32_bf16(a, wf[2][kk], acc2, 0, 0, 0);
        acc3 = __builtin_amdgcn_mfma_f32_16x16x32_bf16(a, wf[3][kk], acc3, 0, 0, 0);
      }
      const int rbase = row0 + mt * 16 + (lane >> 4) * 4;
#pragma unroll
      for (int j = 0; j < 4; ++j) {
        const int rg = rbase + j;
        const float cprev = C0[rg * 128 + hcol];
        const float it = sigm(acc0[j]);
        const float ft = sigm(acc1[j]);
        const float ot = sigm(acc2[j]);
        const float gt = ftanh(acc3[j]);
        const float ct = ft * cprev + it * gt;
        const float ht = ot * ftanh(ct);
        Out[rg * 128 + hcol] = ht;
        Out[BH + rg * 128 + hcol] = ct;
      }
    }
    __syncthreads();
  }
}

extern "C" void kernel_launch(void* const* d_in, const int* in_sizes, int n_in,
                              void* d_out, int out_size, void* d_ws, size_t ws_size,
                              hipStream_t stream) {
  (void)in_sizes; (void)n_in; (void)out_size; (void)d_ws; (void)ws_size;
  lstm_fused<<<256, 512, 0, stream>>>(
      (const float*)d_in[0], (const float*)d_in[1], (const float*)d_in[2],
      (const float*)d_in[3], (const float*)d_in[4], (const float*)d_in[5],
      (const float*)d_in[6], (const float*)d_in[7], (const float*)d_in[8],
      (const float*)d_in[9], (const float*)d_in[10],
      (float*)d_out);
}

// Round 2
// 156.530 us; speedup vs baseline: 1.2197x; 1.2197x over previous
//
#include <hip/hip_runtime.h>

#define BATCH 262144
#define NBLK 256
#define NITER 16          // 4096 tiles / 256 blocks
#define ASTRIDE 264       // 528B row stride: 132 dw = 4 mod 32 banks -> 2-way (free)
#define BH 33554432       // B*H

typedef __attribute__((ext_vector_type(8))) short bf16x8;
typedef __attribute__((ext_vector_type(4))) float f32x4;
typedef __attribute__((ext_vector_type(8))) unsigned short u16x8;

__device__ __forceinline__ unsigned short f2bf(float f) {
  unsigned int u = __float_as_uint(f);
  u += 0x7fffu + ((u >> 16) & 1u);  // round-to-nearest-even
  return (unsigned short)(u >> 16);
}

__device__ __forceinline__ float fexp(float x) { return __builtin_amdgcn_exp2f(x * 1.44269504f); }
__device__ __forceinline__ float sigm(float x) { return __builtin_amdgcn_rcpf(1.f + fexp(-x)); }
__device__ __forceinline__ float ftanh(float x) { return 1.f - 2.f * __builtin_amdgcn_rcpf(1.f + fexp(2.f * x)); }

__global__ __launch_bounds__(512, 2) void lstm_fused(
    const float* __restrict__ X, const float* __restrict__ H0, const float* __restrict__ C0,
    const float* __restrict__ Wii, const float* __restrict__ Whi,
    const float* __restrict__ Wif, const float* __restrict__ Whf,
    const float* __restrict__ Wio, const float* __restrict__ Who,
    const float* __restrict__ Wig, const float* __restrict__ Whg,
    float* __restrict__ Out) {
  __shared__ __align__(16) unsigned short Abuf[64 * ASTRIDE];

  const int tid = threadIdx.x;
  const int wave = tid >> 6;
  const int lane = tid & 63;
  const int lrow = lane & 15;
  const int lk = (lane >> 4) * 8;       // k sub-offset within a 32-wide K tile
  const int hcol = wave * 16 + lrow;    // hidden column this lane produces

  const float* Wxp[4] = {Wii, Wif, Wio, Wig};
  const float* Whp[4] = {Whi, Whf, Who, Whg};

  // ---- load weight fragments once; resident in VGPR/AGPR for the whole kernel ----
  bf16x8 wf[4][8];
#pragma unroll
  for (int g = 0; g < 4; ++g) {
#pragma unroll
    for (int kk = 0; kk < 8; ++kk) {
      const int k = kk * 32 + lk;  // 0..255 over concat(x,h) K axis
      const float* src = (kk < 4) ? (Wxp[g] + hcol * 128 + k)
                                  : (Whp[g] + hcol * 128 + (k - 128));
      float4 lo = *(const float4*)src;
      float4 hi = *(const float4*)(src + 4);
      bf16x8 w;
      w[0] = (short)f2bf(lo.x); w[1] = (short)f2bf(lo.y);
      w[2] = (short)f2bf(lo.z); w[3] = (short)f2bf(lo.w);
      w[4] = (short)f2bf(hi.x); w[5] = (short)f2bf(hi.y);
      w[6] = (short)f2bf(hi.z); w[7] = (short)f2bf(hi.w);
      wf[g][kk] = w;
    }
  }

  // Staging registers for the software pipeline (tile t+1 in flight during compute of t)
  float4 sx[4], sh[4];

  // thread -> 8-elem chunk mapping: f in [0,1024), row = f>>4, col = (f&15)*8
  auto issue_loads = [&](int row0) {
#pragma unroll
    for (int j = 0; j < 2; ++j) {
      const int f = tid + j * 512;
      const int r = f >> 4;
      const int c = (f & 15) * 8;
      const float* px = X + (size_t)(row0 + r) * 128 + c;
      sx[j * 2 + 0] = *(const float4*)px;
      sx[j * 2 + 1] = *(const float4*)(px + 4);
      const float* ph = H0 + (size_t)(row0 + r) * 128 + c;
      sh[j * 2 + 0] = *(const float4*)ph;
      sh[j * 2 + 1] = *(const float4*)(ph + 4);
    }
  };

  issue_loads(blockIdx.x * 64);  // prologue: tile 0 of this block

  for (int it = 0; it < NITER; ++it) {
    const int tile = blockIdx.x + it * NBLK;
    const int row0 = tile * 64;

    __syncthreads();  // all waves done reading Abuf from previous tile

    // ---- convert staged regs -> LDS (bf16), 16B writes ----
#pragma unroll
    for (int j = 0; j < 2; ++j) {
      const int f = tid + j * 512;
      const int r = f >> 4;
      const int c = (f & 15) * 8;
      u16x8 w;
      w[0] = f2bf(sx[j * 2].x);     w[1] = f2bf(sx[j * 2].y);
      w[2] = f2bf(sx[j * 2].z);     w[3] = f2bf(sx[j * 2].w);
      w[4] = f2bf(sx[j * 2 + 1].x); w[5] = f2bf(sx[j * 2 + 1].y);
      w[6] = f2bf(sx[j * 2 + 1].z); w[7] = f2bf(sx[j * 2 + 1].w);
      *(u16x8*)&Abuf[r * ASTRIDE + c] = w;
      u16x8 v;
      v[0] = f2bf(sh[j * 2].x);     v[1] = f2bf(sh[j * 2].y);
      v[2] = f2bf(sh[j * 2].z);     v[3] = f2bf(sh[j * 2].w);
      v[4] = f2bf(sh[j * 2 + 1].x); v[5] = f2bf(sh[j * 2 + 1].y);
      v[6] = f2bf(sh[j * 2 + 1].z); v[7] = f2bf(sh[j * 2 + 1].w);
      *(u16x8*)&Abuf[r * ASTRIDE + 128 + c] = v;
    }

    // issue next tile's global loads now; latency hides under compute below
    if (it + 1 < NITER) issue_loads(row0 + NBLK * 64);

    __syncthreads();  // Abuf ready

    // ---- prefetch C_prev for this tile (latency hidden under MFMA) ----
    const int rb = row0 + (lane >> 4) * 4;
    float cv[16];
#pragma unroll
    for (int mt = 0; mt < 4; ++mt)
#pragma unroll
      for (int j = 0; j < 4; ++j)
        cv[mt * 4 + j] = C0[(size_t)(rb + mt * 16 + j) * 128 + hcol];

    // ---- 4 M-tiles: MFMA all 4 gates, fused LSTM epilogue ----
#pragma unroll
    for (int mt = 0; mt < 4; ++mt) {
      f32x4 acc0 = {0.f, 0.f, 0.f, 0.f};
      f32x4 acc1 = acc0, acc2 = acc0, acc3 = acc0;
#pragma unroll
      for (int kk = 0; kk < 8; ++kk) {
        bf16x8 a = *(const bf16x8*)&Abuf[(mt * 16 + lrow) * ASTRIDE + kk * 32 + lk];
        acc0 = __builtin_amdgcn_mfma_f32_16x16x32_bf16(a, wf[0][kk], acc0, 0, 0, 0);
        acc1 = __builtin_amdgcn_mfma_f32_16x16x32_bf16(a, wf[1][kk], acc1, 0, 0, 0);
        acc2 = __builtin_amdgcn_mfma_f32_16x16x32_bf16(a, wf[2][kk], acc2, 0, 0, 0);
        acc3 = __builtin_amdgcn_mfma_f32_16x16x32_bf16(a, wf[3][kk], acc3, 0, 0, 0);
      }
      const int rbase = rb + mt * 16;
#pragma unroll
      for (int j = 0; j < 4; ++j) {
        const int rg = rbase + j;
        const float cprev = cv[mt * 4 + j];
        const float it_ = sigm(acc0[j]);
        const float ft = sigm(acc1[j]);
        const float ot = sigm(acc2[j]);
        const float gt = ftanh(acc3[j]);
        const float ct = ft * cprev + it_ * gt;
        const float ht = ot * ftanh(ct);
        Out[(size_t)rg * 128 + hcol] = ht;
        Out[BH + (size_t)rg * 128 + hcol] = ct;
      }
    }
  }
}

extern "C" void kernel_launch(void* const* d_in, const int* in_sizes, int n_in,
                              void* d_out, int out_size, void* d_ws, size_t ws_size,
                              hipStream_t stream) {
  (void)in_sizes; (void)n_in; (void)out_size; (void)d_ws; (void)ws_size;
  lstm_fused<<<NBLK, 512, 0, stream>>>(
      (const float*)d_in[0], (const float*)d_in[1], (const float*)d_in[2],
      (const float*)d_in[3], (const float*)d_in[4], (const float*)d_in[5],
      (const float*)d_in[6], (const float*)d_in[7], (const float*)d_in[8],
      (const float*)d_in[9], (const float*)d_in[10],
      (float*)d_out);
}